// Round 11
// baseline (45.022 us; speedup 1.0000x reference)
//
#include <hip/hip_runtime.h>

#define GSZ   64
#define G3    (GSZ * GSZ * GSZ)      // 262144
#define NCAM  8
#define NJ    23
#define IMW   1280
#define IMH   1024
#define HMW   (IMW / 2)              // 640
#define HMH   (IMH / 2)              // 512
#define HWSZ  (HMW * HMH)            // 327680
#define RMAX  32                     // packed-path cap on distinct runs/wave
#define TMAX  12                     // rounds: j = 2t + hi covers j=0..23
#define SSTR  28                     // stage stride: 16B-aligned, 4-way banks (vs 8-way at 24)

__global__ __launch_bounds__(256) void reproj_kernel(
    const float* __restrict__ hm,      // [B, C, J, 512, 640]
    const float* __restrict__ center,  // [B, 3]
    const float* __restrict__ cam,     // [B, C, 4, 3]
    float* __restrict__ out)           // [B, J, 64, 64, 64]
{
#pragma clang fp contract(off)
    const int bid  = blockIdx.x;
    const int b    = bid & 1;                          // batch<->XCD parity
    const int n    = (bid >> 1) * 256 + threadIdx.x;   // z-line waves: lane == z
    const int z = n & 63;
    const int y = (n >> 6) & 63;
    const int x = n >> 12;
    const int lane = threadIdx.x & 63;
    const int wv   = threadIdx.x >> 6;

    // run-fastest slot mapping: lane -> (r = lane&31, j = 2t + lane>>5)
    const int myr  = lane & 31;
    const int hi   = lane >> 5;          // 0 or 1
    const int hiHW = hi * HWSZ;

    __shared__ float sM[NCAM * 12];
    __shared__ int   sOff[4][RMAX];                      // per-wave deduped offsets
    __shared__ __align__(16) float sStage[4][RMAX * SSTR];

    if (threadIdx.x < NCAM * 12) {
        sM[threadIdx.x] = cam[b * NCAM * 12 + threadIdx.x];
    }
    __syncthreads();

    const float cx = center[b * 3 + 0];
    const float cy = center[b * 3 + 1];
    const float cz = center[b * 3 + 2];
    const float px = (float)(x - 32) * 2.0f + cx;
    const float py = (float)(y - 32) * 2.0f + cy;
    const float pz = (float)(z - 32) * 2.0f + cz;

    const float* __restrict__ hmb = hm + (size_t)b * NCAM * NJ * HWSZ;

    // ---- projections + per-camera wave dedup ----
    int off[NCAM], runix[NCAM], Rcnt[NCAM];
    unsigned ldrbits = 0;
#pragma unroll
    for (int c = 0; c < NCAM; ++c) {
        const float* M = &sM[c * 12];
        // XLA/Eigen ordering: sequential FMA along ascending k (bit-exact, R2-verified)
        float p0 = fmaf(pz, M[6], fmaf(py, M[3], px * M[0])) + M[9];
        float p1 = fmaf(pz, M[7], fmaf(py, M[4], px * M[1])) + M[10];
        float p2 = fmaf(pz, M[8], fmaf(py, M[5], px * M[2])) + M[11];
        float u = p0 / p2;              // IEEE divide (no fast-math)
        float v = p1 / p2;
        u = fminf(fmaxf(u, 0.0f), (float)(IMW - 1));
        v = fminf(fmaxf(v, 0.0f), (float)(IMH - 1));
        const int idx = (int)(v * 0.5f) * HMW + (int)(u * 0.5f);
        off[c] = c * (NJ * HWSZ) + idx;

        const int  prev  = __shfl_up(idx, 1);
        const bool start = (lane == 0) || (idx != prev);
        const unsigned long long mask = __ballot(start);
        runix[c] = __popcll(mask & ((2ull << lane) - 1ull)) - 1;
        Rcnt[c]  = __popcll(mask);
        ldrbits |= ((unsigned)start) << c;
    }

    float acc[NJ];
#pragma unroll
    for (int j = 0; j < NJ; ++j) acc[j] = 0.0f;

#pragma unroll
    for (int c = 0; c < NCAM; ++c) {
        const int R     = Rcnt[c];
        const int myrun = runix[c];
        if (R <= RMAX) {
            // leaders publish deduped offsets (same-wave DS ops are in-order)
            if ((ldrbits >> c) & 1u) sOff[wv][myrun] = off[c];
            // ONE lane-indexed offset read per camera (banks 0..31, hi half broadcast)
            const int  po  = sOff[wv][myr];
            const bool rOK = myr < R;

            // A: packed gathers, run-fastest — each half-wave = 32 consecutive
            // run pixels of ONE joint plane => ~2-4 cache lines, not 32.
            float val[TMAX];
#pragma unroll
            for (int t = 0; t < TMAX; ++t) {
                const int j = 2 * t + hi;
                if (rOK && j < NJ) val[t] = hmb[po + hiHW + t * (2 * HWSZ)];
            }
            // B: stage into LDS [run][joint] (stride 28 -> 4-way banks)
#pragma unroll
            for (int t = 0; t < TMAX; ++t) {
                const int j = 2 * t + hi;
                if (rOK && j < NJ) sStage[wv][myr * SSTR + j] = val[t];
            }
            // C: vectorized read-back of my run's 23 joints (6x b128, slot 23 pad ignored)
            const float4* s4 = (const float4*)&sStage[wv][myrun * SSTR];
            const float4 a0 = s4[0], a1 = s4[1], a2 = s4[2],
                         a3 = s4[3], a4 = s4[4], a5 = s4[5];
            acc[ 0] += a0.x; acc[ 1] += a0.y; acc[ 2] += a0.z; acc[ 3] += a0.w;
            acc[ 4] += a1.x; acc[ 5] += a1.y; acc[ 6] += a1.z; acc[ 7] += a1.w;
            acc[ 8] += a2.x; acc[ 9] += a2.y; acc[10] += a2.z; acc[11] += a2.w;
            acc[12] += a3.x; acc[13] += a3.y; acc[14] += a3.z; acc[15] += a3.w;
            acc[16] += a4.x; acc[17] += a4.y; acc[18] += a4.z; acc[19] += a4.w;
            acc[20] += a5.x; acc[21] += a5.y; acc[22] += a5.z;
        } else {
            // rare high-diversity wave: plain per-lane gather
            const int o = off[c];
#pragma unroll
            for (int j = 0; j < NJ; ++j) acc[j] += hmb[o + j * HWSZ];
        }
    }

    float* ob = out + (size_t)b * NJ * G3 + n;
#pragma unroll
    for (int j = 0; j < NJ; ++j) {
        ob[(size_t)j * G3] = acc[j] * 0.125f;
    }
}

extern "C" void kernel_launch(void* const* d_in, const int* in_sizes, int n_in,
                              void* d_out, int out_size, void* d_ws, size_t ws_size,
                              hipStream_t stream) {
    const float* hm     = (const float*)d_in[0];
    const float* center = (const float*)d_in[1];
    const float* cam    = (const float*)d_in[2];
    float* out          = (float*)d_out;

    dim3 grid((G3 / 256) * 2, 1, 1);   // (n-chunk, batch) interleaved on bit 0
    dim3 block(256, 1, 1);
    reproj_kernel<<<grid, block, 0, stream>>>(hm, center, cam, out);
}